// Round 1
// baseline (378.589 us; speedup 1.0000x reference)
//
#include <hip/hip_runtime.h>

// ---------------------------------------------------------------------------
// TopKPooling (PyG-style) on MI355X.
// score = tanh((x @ w) / ||w||)  [replicating XLA's f32 tanh polynomial,
//                                 no-FMA Horner — variant knob for later rounds]
// stable top-k (desc score, asc index) via 4-pass LSD radix sort on
// order-flipped float keys with index payload.
// ---------------------------------------------------------------------------

#define N_NODES 1000000
#define N_EDGES 16000000
#define K_SEL   500000

static constexpr int RTHREADS = 64;                       // 1 wave per radix block
static constexpr int RITEMS   = 32;
static constexpr int RCHUNK   = RTHREADS * RITEMS;        // 2048
static constexpr int NB       = (N_NODES + RCHUNK - 1) / RCHUNK;  // 489
static constexpr int NDIG     = 256;

// --- XLA EmitTanh f32 replica (elemental_ir_emitter). No FMA contraction. ---
__device__ __forceinline__ float tanh_xla(float x) {
  const float kCutoff = 0.0004f;
  const float kClamp  = 7.90531110763549805f;
  float ax = fabsf(x);
  float xc = fminf(fmaxf(x, -kClamp), kClamp);
  float x2 = __fmul_rn(xc, xc);
  float p = -2.76076847742355e-16f;
  p = __fadd_rn(__fmul_rn(p, x2),  2.00018790482477e-13f);
  p = __fadd_rn(__fmul_rn(p, x2), -8.60467152213735e-11f);
  p = __fadd_rn(__fmul_rn(p, x2),  5.12229709037114e-08f);
  p = __fadd_rn(__fmul_rn(p, x2),  1.48572235717979e-05f);
  p = __fadd_rn(__fmul_rn(p, x2),  6.37261928875436e-04f);
  p = __fadd_rn(__fmul_rn(p, x2),  4.89352455891786e-03f);
  float num = __fmul_rn(xc, p);
  float q = 1.19825839466702e-06f;
  q = __fadd_rn(__fmul_rn(q, x2), 1.18534705686654e-04f);
  q = __fadd_rn(__fmul_rn(q, x2), 2.26843463243900e-03f);
  q = __fadd_rn(__fmul_rn(q, x2), 4.89352518554385e-03f);
  float r = __fdiv_rn(num, q);
  return (ax < kCutoff) ? x : r;
}

// score + sortable key (ascending uint == descending score, stable on index).
__global__ void score_kernel(const float* __restrict__ x, const float* __restrict__ w,
                             float* __restrict__ score, unsigned* __restrict__ key,
                             unsigned* __restrict__ pay, int n) {
  int i = blockIdx.x * blockDim.x + threadIdx.x;
  if (i >= n) return;
  float w0 = w[0], w1 = w[1], w2 = w[2];
  // ||w||: left-to-right, no FMA, IEEE sqrt (scalar, identical across threads)
  float nrm = __fsqrt_rn(__fadd_rn(__fadd_rn(__fmul_rn(w0, w0), __fmul_rn(w1, w1)),
                                   __fmul_rn(w2, w2)));
  // dot: left-to-right, no FMA
  float dot = __fadd_rn(__fadd_rn(__fmul_rn(x[3*i+0], w0), __fmul_rn(x[3*i+1], w1)),
                        __fmul_rn(x[3*i+2], w2));
  float z = __fdiv_rn(dot, nrm);
  float s = tanh_xla(z);
  score[i] = s;
  unsigned u = __float_as_uint(s);
  if (u == 0x80000000u) u = 0u;                    // -0 == +0 for ordering
  u = (u & 0x80000000u) ? ~u : (u | 0x80000000u);  // ascending-order map
  key[i] = ~u;                                     // invert -> descending score
  pay[i] = (unsigned)i;
}

// Per-block digit histogram, digit-major layout histDM[d*NB + b].
__global__ void radix_hist(const unsigned* __restrict__ keys, int n,
                           unsigned* __restrict__ histDM, int shift) {
  __shared__ unsigned h[NDIG];
  int t = threadIdx.x;  // 256 threads == NDIG
  h[t] = 0;
  __syncthreads();
  int base = blockIdx.x * RCHUNK;
#pragma unroll
  for (int it = 0; it < RCHUNK / 256; ++it) {
    int i = base + it * 256 + t;
    if (i < n) atomicAdd(&h[(keys[i] >> shift) & 255u], 1u);
  }
  __syncthreads();
  histDM[t * NB + blockIdx.x] = h[t];
}

// Exclusive scan of each digit row (NB entries); rowsum[d] = row total.
__global__ void scan_rows(unsigned* __restrict__ histDM, unsigned* __restrict__ rowsum) {
  __shared__ unsigned lds[512];
  int d = blockIdx.x, t = threadIdx.x;  // 512 threads, NB=489 fits one tile
  unsigned v = (t < NB) ? histDM[d * NB + t] : 0u;
  lds[t] = v;
  __syncthreads();
#pragma unroll
  for (int off = 1; off < 512; off <<= 1) {
    unsigned add = (t >= off) ? lds[t - off] : 0u;
    __syncthreads();
    lds[t] += add;
    __syncthreads();
  }
  if (t < NB) histDM[d * NB + t] = lds[t] - v;
  if (t == 511) rowsum[d] = lds[511];
}

// Exclusive scan of the 256 digit totals.
__global__ void scan_base(const unsigned* __restrict__ rowsum, unsigned* __restrict__ rowbase) {
  __shared__ unsigned lds[NDIG];
  int t = threadIdx.x;
  unsigned v = rowsum[t];
  lds[t] = v;
  __syncthreads();
#pragma unroll
  for (int off = 1; off < NDIG; off <<= 1) {
    unsigned add = (t >= off) ? lds[t - off] : 0u;
    __syncthreads();
    lds[t] += add;
    __syncthreads();
  }
  rowbase[t] = lds[t] - v;
}

// Stable scatter: blocked ownership (thread t owns items [t*RITEMS, ...)) so
// within-chunk ranks preserve original order -> LSD stability -> jax top_k
// tie rule (lower index first) reproduced exactly.
__global__ __launch_bounds__(RTHREADS) void radix_scatter(
    const unsigned* __restrict__ kin, const unsigned* __restrict__ pin, int n,
    const unsigned* __restrict__ histDM, const unsigned* __restrict__ rowbase,
    unsigned* __restrict__ kout, unsigned* __restrict__ pout, int shift) {
  __shared__ unsigned short mat[RTHREADS][NDIG];  // 32 KiB
  __shared__ unsigned off[NDIG];
  int t = threadIdx.x, b = blockIdx.x;
#pragma unroll
  for (int d = 0; d < NDIG; ++d) mat[t][d] = 0;
#pragma unroll
  for (int j = 0; j < NDIG / RTHREADS; ++j) {
    int d = t + j * RTHREADS;
    off[d] = rowbase[d] + histDM[d * NB + b];
  }
  int base = b * RCHUNK + t * RITEMS;
  unsigned k[RITEMS], p[RITEMS];
#pragma unroll
  for (int m = 0; m < RITEMS; ++m) {
    if (base + m < n) { k[m] = kin[base + m]; p[m] = pin[base + m]; }
    else              { k[m] = 0u;            p[m] = 0u; }
  }
#pragma unroll
  for (int m = 0; m < RITEMS; ++m)
    if (base + m < n) mat[t][(k[m] >> shift) & 255u]++;
  __syncthreads();
  // column-wise exclusive scan over threads (stable rank base per thread)
#pragma unroll
  for (int j = 0; j < NDIG / RTHREADS; ++j) {
    int d = t + j * RTHREADS;
    unsigned run = 0;
    for (int tt = 0; tt < RTHREADS; ++tt) {
      unsigned v = mat[tt][d];
      mat[tt][d] = (unsigned short)run;
      run += v;
    }
  }
  __syncthreads();
#pragma unroll
  for (int m = 0; m < RITEMS; ++m) {
    if (base + m < n) {
      unsigned d = (k[m] >> shift) & 255u;
      unsigned r = mat[t][d]++;               // sequential per thread -> stable
      unsigned pos = off[d] + r;
      kout[pos] = k[m];
      pout[pos] = p[m];
    }
  }
}

__global__ void init_newidx(int* __restrict__ ni, int n) {
  int i = blockIdx.x * blockDim.x + threadIdx.x;
  if (i < n) ni[i] = -1;
}

// new_idx scatter + gated x_out, fused.
__global__ void select_kernel(const unsigned* __restrict__ pay, const float* __restrict__ score,
                              const float* __restrict__ x, int* __restrict__ ni,
                              float* __restrict__ xout, int k) {
  int i = blockIdx.x * blockDim.x + threadIdx.x;
  if (i >= k) return;
  int pidx = (int)pay[i];
  ni[pidx] = i;
  float s = score[pidx];
  xout[3*i+0] = __fmul_rn(x[3*pidx+0], s);
  xout[3*i+1] = __fmul_rn(x[3*pidx+1], s);
  xout[3*i+2] = __fmul_rn(x[3*pidx+2], s);
}

// Relabel edges + mask. 4 edges/thread, int4/float4 vector path.
__global__ void edge_kernel(const int* __restrict__ ei, const int* __restrict__ ni,
                            float* __restrict__ oedge, float* __restrict__ omask) {
  long long i = (long long)blockIdx.x * blockDim.x + threadIdx.x;
  long long e = i * 4;
  if (e >= (long long)N_EDGES) return;
  const int4 a = *(const int4*)(ei + e);
  const int4 b = *(const int4*)(ei + (long long)N_EDGES + e);
  int na0 = ni[a.x], na1 = ni[a.y], na2 = ni[a.z], na3 = ni[a.w];
  int nb0 = ni[b.x], nb1 = ni[b.y], nb2 = ni[b.z], nb3 = ni[b.w];
  bool m0 = (na0 >= 0) && (nb0 >= 0);
  bool m1 = (na1 >= 0) && (nb1 >= 0);
  bool m2 = (na2 >= 0) && (nb2 >= 0);
  bool m3 = (na3 >= 0) && (nb3 >= 0);
  float4 oa = make_float4(m0 ? (float)na0 : -1.0f, m1 ? (float)na1 : -1.0f,
                          m2 ? (float)na2 : -1.0f, m3 ? (float)na3 : -1.0f);
  float4 ob = make_float4(m0 ? (float)nb0 : -1.0f, m1 ? (float)nb1 : -1.0f,
                          m2 ? (float)nb2 : -1.0f, m3 ? (float)nb3 : -1.0f);
  float4 om = make_float4(m0 ? 1.0f : 0.0f, m1 ? 1.0f : 0.0f,
                          m2 ? 1.0f : 0.0f, m3 ? 1.0f : 0.0f);
  *(float4*)(oedge + e) = oa;
  *(float4*)(oedge + (long long)N_EDGES + e) = ob;
  *(float4*)(omask + e) = om;
}

extern "C" void kernel_launch(void* const* d_in, const int* in_sizes, int n_in,
                              void* d_out, int out_size, void* d_ws, size_t ws_size,
                              hipStream_t stream) {
  const float* x  = (const float*)d_in[0];
  const int*   ei = (const int*)d_in[1];
  const float* w  = (const float*)d_in[2];
  float* out = (float*)d_out;

  // workspace carve-out (~24.5 MB)
  char* ws = (char*)d_ws;
  size_t off = 0;
  auto alloc = [&](size_t bytes) -> void* {
    void* ptr = ws + off;
    off += (bytes + 255) & ~size_t(255);
    return ptr;
  };
  float*    score  = (float*)alloc((size_t)N_NODES * 4);
  unsigned* key0   = (unsigned*)alloc((size_t)N_NODES * 4);
  unsigned* pay0   = (unsigned*)alloc((size_t)N_NODES * 4);
  unsigned* key1   = (unsigned*)alloc((size_t)N_NODES * 4);
  unsigned* pay1   = (unsigned*)alloc((size_t)N_NODES * 4);
  unsigned* histDM = (unsigned*)alloc((size_t)NDIG * NB * 4);
  unsigned* rowsum = (unsigned*)alloc((size_t)NDIG * 4);
  unsigned* rowbase= (unsigned*)alloc((size_t)NDIG * 4);
  int*      ni     = (int*)alloc((size_t)N_NODES * 4);
  (void)ws_size; (void)in_sizes; (void)n_in; (void)out_size;

  score_kernel<<<(N_NODES + 255) / 256, 256, 0, stream>>>(x, w, score, key0, pay0, N_NODES);

  unsigned* kb[2][2] = {{key0, pay0}, {key1, pay1}};
  int cur = 0;
  for (int pass = 0; pass < 4; ++pass) {
    int shift = pass * 8;
    radix_hist   <<<NB,   256, 0, stream>>>(kb[cur][0], N_NODES, histDM, shift);
    scan_rows    <<<NDIG, 512, 0, stream>>>(histDM, rowsum);
    scan_base    <<<1,   NDIG, 0, stream>>>(rowsum, rowbase);
    radix_scatter<<<NB, RTHREADS, 0, stream>>>(kb[cur][0], kb[cur][1], N_NODES,
                                               histDM, rowbase,
                                               kb[cur ^ 1][0], kb[cur ^ 1][1], shift);
    cur ^= 1;
  }
  // 4 passes -> sorted (key,payload) back in buffer set 0
  init_newidx <<<(N_NODES + 255) / 256, 256, 0, stream>>>(ni, N_NODES);
  select_kernel<<<(K_SEL + 255) / 256, 256, 0, stream>>>(kb[cur][1], score, x, ni, out, K_SEL);
  edge_kernel <<<(N_EDGES / 4 + 255) / 256, 256, 0, stream>>>(ei, ni,
                                                              out + 1500000,   // new_edges
                                                              out + 33500000); // edge_mask
}

// Round 2
// 328.378 us; speedup vs baseline: 1.1529x; 1.1529x over previous
//
#include <hip/hip_runtime.h>

// ---------------------------------------------------------------------------
// TopKPooling (PyG-style) on MI355X.
// score = tanh((x @ w) / ||w||)  [XLA EmitTanh f32 replica — DO NOT TOUCH,
//                                 bit-exactness validated in round 1]
// stable top-k via 4-pass LSD radix sort (ballot-ranked scatter), then
// fused select + nt-streaming edge relabel.
// ---------------------------------------------------------------------------

#define N_NODES 1000000
#define N_EDGES 16000000
#define K_SEL   500000

typedef int   v4i __attribute__((ext_vector_type(4)));
typedef float v4f __attribute__((ext_vector_type(4)));

static constexpr int NDIG     = 256;
static constexpr int STHREADS = 256;                 // 4 waves
static constexpr int SIPT     = 8;
static constexpr int SCHUNK   = STHREADS * SIPT;     // 2048
static constexpr int NB       = (N_NODES + SCHUNK - 1) / SCHUNK;  // 489
static constexpr int NWAVE    = STHREADS / 64;

// --- XLA EmitTanh f32 replica (elemental_ir_emitter). No FMA contraction. ---
__device__ __forceinline__ float tanh_xla(float x) {
  const float kCutoff = 0.0004f;
  const float kClamp  = 7.90531110763549805f;
  float ax = fabsf(x);
  float xc = fminf(fmaxf(x, -kClamp), kClamp);
  float x2 = __fmul_rn(xc, xc);
  float p = -2.76076847742355e-16f;
  p = __fadd_rn(__fmul_rn(p, x2),  2.00018790482477e-13f);
  p = __fadd_rn(__fmul_rn(p, x2), -8.60467152213735e-11f);
  p = __fadd_rn(__fmul_rn(p, x2),  5.12229709037114e-08f);
  p = __fadd_rn(__fmul_rn(p, x2),  1.48572235717979e-05f);
  p = __fadd_rn(__fmul_rn(p, x2),  6.37261928875436e-04f);
  p = __fadd_rn(__fmul_rn(p, x2),  4.89352455891786e-03f);
  float num = __fmul_rn(xc, p);
  float q = 1.19825839466702e-06f;
  q = __fadd_rn(__fmul_rn(q, x2), 1.18534705686654e-04f);
  q = __fadd_rn(__fmul_rn(q, x2), 2.26843463243900e-03f);
  q = __fadd_rn(__fmul_rn(q, x2), 4.89352518554385e-03f);
  float r = __fdiv_rn(num, q);
  return (ax < kCutoff) ? x : r;
}

__global__ void score_kernel(const float* __restrict__ x, const float* __restrict__ w,
                             float* __restrict__ score, unsigned* __restrict__ key,
                             unsigned* __restrict__ pay, int n) {
  int i = blockIdx.x * blockDim.x + threadIdx.x;
  if (i >= n) return;
  float w0 = w[0], w1 = w[1], w2 = w[2];
  float nrm = __fsqrt_rn(__fadd_rn(__fadd_rn(__fmul_rn(w0, w0), __fmul_rn(w1, w1)),
                                   __fmul_rn(w2, w2)));
  float dot = __fadd_rn(__fadd_rn(__fmul_rn(x[3*i+0], w0), __fmul_rn(x[3*i+1], w1)),
                        __fmul_rn(x[3*i+2], w2));
  float z = __fdiv_rn(dot, nrm);
  float s = tanh_xla(z);
  score[i] = s;
  unsigned u = __float_as_uint(s);
  if (u == 0x80000000u) u = 0u;                    // -0 == +0 for ordering
  u = (u & 0x80000000u) ? ~u : (u | 0x80000000u);  // ascending-order map
  key[i] = ~u;                                     // invert -> descending score
  pay[i] = (unsigned)i;
}

// Per-block digit histogram, digit-major layout histDM[d*NB + b].
__global__ void radix_hist(const unsigned* __restrict__ keys, int n,
                           unsigned* __restrict__ histDM, int shift) {
  __shared__ unsigned h[NDIG];
  int t = threadIdx.x;  // 256 threads == NDIG
  h[t] = 0;
  __syncthreads();
  int base = blockIdx.x * SCHUNK;
#pragma unroll
  for (int it = 0; it < SCHUNK / 256; ++it) {
    int i = base + it * 256 + t;
    if (i < n) atomicAdd(&h[(keys[i] >> shift) & 255u], 1u);
  }
  __syncthreads();
  histDM[t * NB + blockIdx.x] = h[t];
}

// Exclusive scan of each digit row (NB entries); rowsum[d] = row total.
__global__ void scan_rows(unsigned* __restrict__ histDM, unsigned* __restrict__ rowsum) {
  __shared__ unsigned lds[512];
  int d = blockIdx.x, t = threadIdx.x;
  unsigned v = (t < NB) ? histDM[d * NB + t] : 0u;
  lds[t] = v;
  __syncthreads();
#pragma unroll
  for (int off = 1; off < 512; off <<= 1) {
    unsigned add = (t >= off) ? lds[t - off] : 0u;
    __syncthreads();
    lds[t] += add;
    __syncthreads();
  }
  if (t < NB) histDM[d * NB + t] = lds[t] - v;
  if (t == 511) rowsum[d] = lds[511];
}

__global__ void scan_base(const unsigned* __restrict__ rowsum, unsigned* __restrict__ rowbase) {
  __shared__ unsigned lds[NDIG];
  int t = threadIdx.x;
  unsigned v = rowsum[t];
  lds[t] = v;
  __syncthreads();
#pragma unroll
  for (int off = 1; off < NDIG; off <<= 1) {
    unsigned add = (t >= off) ? lds[t - off] : 0u;
    __syncthreads();
    lds[t] += add;
    __syncthreads();
  }
  rowbase[t] = lds[t] - v;
}

// Stable scatter, v2: 4 waves, ballot match-ranking, LDS reorder for
// digit-run-coalesced global writes. Item order = (s, wave, lane) = original.
__global__ __launch_bounds__(STHREADS) void radix_scatter(
    const unsigned* __restrict__ kin, const unsigned* __restrict__ pin, int n,
    const unsigned* __restrict__ histDM, const unsigned* __restrict__ rowbase,
    unsigned* __restrict__ kout, unsigned* __restrict__ pout, int shift) {
  __shared__ unsigned short whist[SIPT][NWAVE][NDIG];  // 16 KiB
  __shared__ unsigned goff[NDIG];
  __shared__ unsigned bexcl[NDIG];
  __shared__ unsigned scanbuf[NDIG];
  __shared__ unsigned lkey[SCHUNK];                    // 8 KiB
  __shared__ unsigned lpay[SCHUNK];                    // 8 KiB
  int t = threadIdx.x, b = blockIdx.x;
  int wave = t >> 6, lane = t & 63;
  for (int j = t; j < SIPT * NWAVE * NDIG; j += STHREADS)
    ((unsigned short*)whist)[j] = 0;
  goff[t] = rowbase[t] + histDM[t * NB + b];
  __syncthreads();

  unsigned k[SIPT], p[SIPT], dg[SIPT], lr[SIPT];
  bool val[SIPT];
  int base = b * SCHUNK;
#pragma unroll
  for (int s = 0; s < SIPT; ++s) {
    int i = base + s * STHREADS + t;
    val[s] = (i < n);
    k[s] = val[s] ? kin[i] : 0u;
    p[s] = val[s] ? pin[i] : 0u;
    dg[s] = (k[s] >> shift) & 255u;
  }
#pragma unroll
  for (int s = 0; s < SIPT; ++s) {
    unsigned long long m = ~0ull;
#pragma unroll
    for (int bb = 0; bb < 8; ++bb) {
      unsigned long long vote = __ballot((dg[s] >> bb) & 1u);
      m &= ((dg[s] >> bb) & 1u) ? vote : ~vote;
    }
    m &= __ballot(val[s]);
    lr[s] = (unsigned)__popcll(m & ((1ull << lane) - 1ull));
    if (val[s] && lr[s] == 0)  // leader: lowest valid lane of its digit group
      whist[s][wave][dg[s]] = (unsigned short)__popcll(m);
  }
  __syncthreads();
  // per-digit serial prefix over (s,wave) in item order; total -> scanbuf
  unsigned run = 0;
#pragma unroll
  for (int s = 0; s < SIPT; ++s)
#pragma unroll
    for (int w = 0; w < NWAVE; ++w) {
      unsigned c = whist[s][w][t];
      whist[s][w][t] = (unsigned short)run;
      run += c;
    }
  scanbuf[t] = run;
  __syncthreads();
#pragma unroll
  for (int o = 1; o < NDIG; o <<= 1) {
    unsigned add = (t >= o) ? scanbuf[t - o] : 0u;
    __syncthreads();
    scanbuf[t] += add;
    __syncthreads();
  }
  bexcl[t] = scanbuf[t] - run;
  __syncthreads();
  // local counting-sort reorder into LDS
#pragma unroll
  for (int s = 0; s < SIPT; ++s) {
    if (val[s]) {
      unsigned lp = bexcl[dg[s]] + (unsigned)whist[s][wave][dg[s]] + lr[s];
      lkey[lp] = k[s];
      lpay[lp] = p[s];
    }
  }
  __syncthreads();
  // contiguous LDS read -> digit-run-coalesced global write
  int nvalid = min(n - base, SCHUNK);
#pragma unroll
  for (int s = 0; s < SIPT; ++s) {
    int j = s * STHREADS + t;
    if (j < nvalid) {
      unsigned kk = lkey[j], pp = lpay[j];
      unsigned d = (kk >> shift) & 255u;
      unsigned gpos = goff[d] + ((unsigned)j - bexcl[d]);
      kout[gpos] = kk;
      pout[gpos] = pp;
    }
  }
}

__global__ void init_newidx(int* __restrict__ ni, int n) {
  int i = blockIdx.x * blockDim.x + threadIdx.x;
  if (i < n) ni[i] = -1;
}

__global__ void select_kernel(const unsigned* __restrict__ pay, const float* __restrict__ score,
                              const float* __restrict__ x, int* __restrict__ ni,
                              float* __restrict__ xout, int k) {
  int i = blockIdx.x * blockDim.x + threadIdx.x;
  if (i >= k) return;
  int pidx = (int)pay[i];
  ni[pidx] = i;
  float s = score[pidx];
  xout[3*i+0] = __fmul_rn(x[3*pidx+0], s);
  xout[3*i+1] = __fmul_rn(x[3*pidx+1], s);
  xout[3*i+2] = __fmul_rn(x[3*pidx+2], s);
}

// Relabel edges + mask. 8 edges/thread; nt streaming loads/stores keep the
// 4MB ni table resident in per-XCD L2.
__global__ __launch_bounds__(256) void edge_kernel(
    const int* __restrict__ ei, const int* __restrict__ ni,
    float* __restrict__ oedge, float* __restrict__ omask) {
  long long e = ((long long)blockIdx.x * 256 + threadIdx.x) * 8;
  if (e >= (long long)N_EDGES) return;
  const v4i a0 = __builtin_nontemporal_load((const v4i*)(ei + e));
  const v4i a1 = __builtin_nontemporal_load((const v4i*)(ei + e) + 1);
  const v4i b0 = __builtin_nontemporal_load((const v4i*)(ei + (long long)N_EDGES + e));
  const v4i b1 = __builtin_nontemporal_load((const v4i*)(ei + (long long)N_EDGES + e) + 1);
  int na[8], nb[8];
#pragma unroll
  for (int j = 0; j < 4; ++j) {
    na[j]     = ni[a0[j]];
    na[4 + j] = ni[a1[j]];
    nb[j]     = ni[b0[j]];
    nb[4 + j] = ni[b1[j]];
  }
  float fa[8], fb[8], fm[8];
#pragma unroll
  for (int j = 0; j < 8; ++j) {
    bool m = (na[j] >= 0) && (nb[j] >= 0);
    fa[j] = m ? (float)na[j] : -1.0f;
    fb[j] = m ? (float)nb[j] : -1.0f;
    fm[j] = m ? 1.0f : 0.0f;
  }
  __builtin_nontemporal_store(*(const v4f*)&fa[0], (v4f*)(oedge + e));
  __builtin_nontemporal_store(*(const v4f*)&fa[4], (v4f*)(oedge + e) + 1);
  __builtin_nontemporal_store(*(const v4f*)&fb[0], (v4f*)(oedge + (long long)N_EDGES + e));
  __builtin_nontemporal_store(*(const v4f*)&fb[4], (v4f*)(oedge + (long long)N_EDGES + e) + 1);
  __builtin_nontemporal_store(*(const v4f*)&fm[0], (v4f*)(omask + e));
  __builtin_nontemporal_store(*(const v4f*)&fm[4], (v4f*)(omask + e) + 1);
}

extern "C" void kernel_launch(void* const* d_in, const int* in_sizes, int n_in,
                              void* d_out, int out_size, void* d_ws, size_t ws_size,
                              hipStream_t stream) {
  const float* x  = (const float*)d_in[0];
  const int*   ei = (const int*)d_in[1];
  const float* w  = (const float*)d_in[2];
  float* out = (float*)d_out;

  char* ws = (char*)d_ws;
  size_t off = 0;
  auto alloc = [&](size_t bytes) -> void* {
    void* ptr = ws + off;
    off += (bytes + 255) & ~size_t(255);
    return ptr;
  };
  float*    score  = (float*)alloc((size_t)N_NODES * 4);
  unsigned* key0   = (unsigned*)alloc((size_t)N_NODES * 4);
  unsigned* pay0   = (unsigned*)alloc((size_t)N_NODES * 4);
  unsigned* key1   = (unsigned*)alloc((size_t)N_NODES * 4);
  unsigned* pay1   = (unsigned*)alloc((size_t)N_NODES * 4);
  unsigned* histDM = (unsigned*)alloc((size_t)NDIG * NB * 4);
  unsigned* rowsum = (unsigned*)alloc((size_t)NDIG * 4);
  unsigned* rowbase= (unsigned*)alloc((size_t)NDIG * 4);
  int*      ni     = (int*)alloc((size_t)N_NODES * 4);
  (void)ws_size; (void)in_sizes; (void)n_in; (void)out_size;

  score_kernel<<<(N_NODES + 255) / 256, 256, 0, stream>>>(x, w, score, key0, pay0, N_NODES);

  unsigned* kb[2][2] = {{key0, pay0}, {key1, pay1}};
  int cur = 0;
  for (int pass = 0; pass < 4; ++pass) {
    int shift = pass * 8;
    radix_hist   <<<NB,   256, 0, stream>>>(kb[cur][0], N_NODES, histDM, shift);
    scan_rows    <<<NDIG, 512, 0, stream>>>(histDM, rowsum);
    scan_base    <<<1,   NDIG, 0, stream>>>(rowsum, rowbase);
    radix_scatter<<<NB, STHREADS, 0, stream>>>(kb[cur][0], kb[cur][1], N_NODES,
                                               histDM, rowbase,
                                               kb[cur ^ 1][0], kb[cur ^ 1][1], shift);
    cur ^= 1;
  }
  init_newidx <<<(N_NODES + 255) / 256, 256, 0, stream>>>(ni, N_NODES);
  select_kernel<<<(K_SEL + 255) / 256, 256, 0, stream>>>(kb[cur][1], score, x, ni, out, K_SEL);
  edge_kernel <<<(N_EDGES / 8 + 255) / 256, 256, 0, stream>>>(ei, ni,
                                                              out + 1500000,   // new_edges
                                                              out + 33500000); // edge_mask
}

// Round 3
// 230.066 us; speedup vs baseline: 1.6456x; 1.4273x over previous
//
#include <hip/hip_runtime.h>

// ---------------------------------------------------------------------------
// TopKPooling (PyG-style) on MI355X.
// score = tanh((x @ w) / ||w||)  [XLA EmitTanh f32 replica — DO NOT TOUCH,
//                                 bit-exactness validated in round 1]
// stable top-k via 4-pass LSD radix sort on packed u64 (key<<32 | idx),
// ballot-ranked scatter; edge relabel via LDS-bitmap membership test
// (two 64KB phases) so only ~25% of edges gather the ni table.
// ---------------------------------------------------------------------------

#define N_NODES 1000000
#define N_EDGES 16000000
#define K_SEL   500000

typedef int      v4i __attribute__((ext_vector_type(4)));
typedef float    v4f __attribute__((ext_vector_type(4)));
typedef unsigned v4u __attribute__((ext_vector_type(4)));
typedef unsigned long long u64;

static constexpr int NDIG     = 256;
static constexpr int STHREADS = 256;                 // 4 waves
static constexpr int SIPT     = 8;
static constexpr int SCHUNK   = STHREADS * SIPT;     // 2048
static constexpr int NB       = (N_NODES + SCHUNK - 1) / SCHUNK;  // 489
static constexpr int NWAVE    = STHREADS / 64;

static constexpr int EB_THREADS = 1024;
static constexpr int EB_EDGES   = EB_THREADS * 8;    // 8192
static constexpr int NODE_SPLIT = 524288;            // word-aligned split
static constexpr int BM_WORDS   = (N_NODES + 31) / 32;   // 31250
static constexpr int BM_W0      = NODE_SPLIT / 32;       // 16384 (64 KiB)
static constexpr int BM_W1      = BM_WORDS - BM_W0;      // 14866
static constexpr int BM_ALLOC   = 31264;                 // padded for x4 stage

// --- XLA EmitTanh f32 replica (elemental_ir_emitter). No FMA contraction. ---
__device__ __forceinline__ float tanh_xla(float x) {
  const float kCutoff = 0.0004f;
  const float kClamp  = 7.90531110763549805f;
  float ax = fabsf(x);
  float xc = fminf(fmaxf(x, -kClamp), kClamp);
  float x2 = __fmul_rn(xc, xc);
  float p = -2.76076847742355e-16f;
  p = __fadd_rn(__fmul_rn(p, x2),  2.00018790482477e-13f);
  p = __fadd_rn(__fmul_rn(p, x2), -8.60467152213735e-11f);
  p = __fadd_rn(__fmul_rn(p, x2),  5.12229709037114e-08f);
  p = __fadd_rn(__fmul_rn(p, x2),  1.48572235717979e-05f);
  p = __fadd_rn(__fmul_rn(p, x2),  6.37261928875436e-04f);
  p = __fadd_rn(__fmul_rn(p, x2),  4.89352455891786e-03f);
  float num = __fmul_rn(xc, p);
  float q = 1.19825839466702e-06f;
  q = __fadd_rn(__fmul_rn(q, x2), 1.18534705686654e-04f);
  q = __fadd_rn(__fmul_rn(q, x2), 2.26843463243900e-03f);
  q = __fadd_rn(__fmul_rn(q, x2), 4.89352518554385e-03f);
  float r = __fdiv_rn(num, q);
  return (ax < kCutoff) ? x : r;
}

__global__ void score_kernel(const float* __restrict__ x, const float* __restrict__ w,
                             float* __restrict__ score, u64* __restrict__ kp, int n) {
  int i = blockIdx.x * blockDim.x + threadIdx.x;
  if (i >= n) return;
  float w0 = w[0], w1 = w[1], w2 = w[2];
  float nrm = __fsqrt_rn(__fadd_rn(__fadd_rn(__fmul_rn(w0, w0), __fmul_rn(w1, w1)),
                                   __fmul_rn(w2, w2)));
  float dot = __fadd_rn(__fadd_rn(__fmul_rn(x[3*i+0], w0), __fmul_rn(x[3*i+1], w1)),
                        __fmul_rn(x[3*i+2], w2));
  float z = __fdiv_rn(dot, nrm);
  float s = tanh_xla(z);
  score[i] = s;
  unsigned u = __float_as_uint(s);
  if (u == 0x80000000u) u = 0u;                    // -0 == +0 for ordering
  u = (u & 0x80000000u) ? ~u : (u | 0x80000000u);  // ascending-order map
  kp[i] = ((u64)(~u) << 32) | (unsigned)i;         // descending score, stable
}

// Per-block digit histogram, digit-major layout histDM[d*NB + b].
__global__ void radix_hist(const u64* __restrict__ kp, int n,
                           unsigned* __restrict__ histDM, int shift) {
  __shared__ unsigned h[NDIG];
  int t = threadIdx.x;  // 256 threads == NDIG
  h[t] = 0;
  __syncthreads();
  int base = blockIdx.x * SCHUNK;
#pragma unroll
  for (int it = 0; it < SCHUNK / 256; ++it) {
    int i = base + it * 256 + t;
    if (i < n) atomicAdd(&h[(unsigned)(kp[i] >> (32 + shift)) & 255u], 1u);
  }
  __syncthreads();
  histDM[t * NB + blockIdx.x] = h[t];
}

// Exclusive scan of each digit row (NB entries); rowsum[d] = row total.
__global__ void scan_rows(unsigned* __restrict__ histDM, unsigned* __restrict__ rowsum) {
  __shared__ unsigned lds[512];
  int d = blockIdx.x, t = threadIdx.x;
  unsigned v = (t < NB) ? histDM[d * NB + t] : 0u;
  lds[t] = v;
  __syncthreads();
#pragma unroll
  for (int off = 1; off < 512; off <<= 1) {
    unsigned add = (t >= off) ? lds[t - off] : 0u;
    __syncthreads();
    lds[t] += add;
    __syncthreads();
  }
  if (t < NB) histDM[d * NB + t] = lds[t] - v;
  if (t == 511) rowsum[d] = lds[511];
}

// Stable scatter: ballot match-ranking + LDS reorder; rowbase scan folded in.
__global__ __launch_bounds__(STHREADS) void radix_scatter(
    const u64* __restrict__ kpin, int n,
    const unsigned* __restrict__ histDM, const unsigned* __restrict__ rowsum,
    u64* __restrict__ kpout, int shift) {
  __shared__ unsigned short whist[SIPT][NWAVE][NDIG];  // 16 KiB
  __shared__ unsigned goff[NDIG];
  __shared__ unsigned bexcl[NDIG];
  __shared__ unsigned scanbuf[NDIG];
  __shared__ u64 lkp[SCHUNK];                          // 16 KiB
  int t = threadIdx.x, b = blockIdx.x;
  int wave = t >> 6, lane = t & 63;
  for (int j = t; j < SIPT * NWAVE * NDIG; j += STHREADS)
    ((unsigned short*)whist)[j] = 0;
  // rowbase = exclusive scan of rowsum (256 entries, cheap per block)
  unsigned rs = rowsum[t];
  scanbuf[t] = rs;
  __syncthreads();
#pragma unroll
  for (int o = 1; o < NDIG; o <<= 1) {
    unsigned add = (t >= o) ? scanbuf[t - o] : 0u;
    __syncthreads();
    scanbuf[t] += add;
    __syncthreads();
  }
  goff[t] = (scanbuf[t] - rs) + histDM[t * NB + b];
  __syncthreads();

  u64 k[SIPT];
  unsigned dg[SIPT], lr[SIPT];
  bool val[SIPT];
  int base = b * SCHUNK;
#pragma unroll
  for (int s = 0; s < SIPT; ++s) {
    int i = base + s * STHREADS + t;
    val[s] = (i < n);
    k[s] = val[s] ? kpin[i] : 0ull;
    dg[s] = (unsigned)(k[s] >> (32 + shift)) & 255u;
  }
#pragma unroll
  for (int s = 0; s < SIPT; ++s) {
    unsigned long long m = ~0ull;
#pragma unroll
    for (int bb = 0; bb < 8; ++bb) {
      unsigned long long vote = __ballot((dg[s] >> bb) & 1u);
      m &= ((dg[s] >> bb) & 1u) ? vote : ~vote;
    }
    m &= __ballot(val[s]);
    lr[s] = (unsigned)__popcll(m & ((1ull << lane) - 1ull));
    if (val[s] && lr[s] == 0)  // leader: lowest valid lane of its digit group
      whist[s][wave][dg[s]] = (unsigned short)__popcll(m);
  }
  __syncthreads();
  // per-digit serial prefix over (s,wave) in item order; total -> scanbuf
  unsigned run = 0;
#pragma unroll
  for (int s = 0; s < SIPT; ++s)
#pragma unroll
    for (int w = 0; w < NWAVE; ++w) {
      unsigned c = whist[s][w][t];
      whist[s][w][t] = (unsigned short)run;
      run += c;
    }
  scanbuf[t] = run;
  __syncthreads();
#pragma unroll
  for (int o = 1; o < NDIG; o <<= 1) {
    unsigned add = (t >= o) ? scanbuf[t - o] : 0u;
    __syncthreads();
    scanbuf[t] += add;
    __syncthreads();
  }
  bexcl[t] = scanbuf[t] - run;
  __syncthreads();
  // local counting-sort reorder into LDS
#pragma unroll
  for (int s = 0; s < SIPT; ++s) {
    if (val[s]) {
      unsigned lp = bexcl[dg[s]] + (unsigned)whist[s][wave][dg[s]] + lr[s];
      lkp[lp] = k[s];
    }
  }
  __syncthreads();
  // contiguous LDS read -> digit-run-coalesced global write
  int nvalid = min(n - base, SCHUNK);
#pragma unroll
  for (int s = 0; s < SIPT; ++s) {
    int j = s * STHREADS + t;
    if (j < nvalid) {
      u64 kk = lkp[j];
      unsigned d = (unsigned)(kk >> (32 + shift)) & 255u;
      unsigned gpos = goff[d] + ((unsigned)j - bexcl[d]);
      kpout[gpos] = kk;
    }
  }
}

// ni = -1 everywhere; bitmap = 0.
__global__ void init_kernel(int* __restrict__ ni, unsigned* __restrict__ bm, int n) {
  int i = blockIdx.x * blockDim.x + threadIdx.x;
  if (i < n) ni[i] = -1;
  if (i < BM_ALLOC) bm[i] = 0u;
}

// new_idx scatter + gated x_out + selected-bitmap build, fused.
__global__ void select_kernel(const u64* __restrict__ kp, const float* __restrict__ score,
                              const float* __restrict__ x, int* __restrict__ ni,
                              unsigned* __restrict__ bm, float* __restrict__ xout, int k) {
  int i = blockIdx.x * blockDim.x + threadIdx.x;
  if (i >= k) return;
  int pidx = (int)(unsigned)(kp[i] & 0xFFFFFFFFull);
  ni[pidx] = i;
  atomicOr(&bm[pidx >> 5], 1u << (pidx & 31));
  float s = score[pidx];
  xout[3*i+0] = __fmul_rn(x[3*pidx+0], s);
  xout[3*i+1] = __fmul_rn(x[3*pidx+1], s);
  xout[3*i+2] = __fmul_rn(x[3*pidx+2], s);
}

// Relabel edges + mask. Membership test via LDS bitmap (two 64KB phases);
// ni gathered only for surviving edges (~25%).
__global__ __launch_bounds__(EB_THREADS) void edge_kernel(
    const int* __restrict__ ei, const int* __restrict__ ni,
    const unsigned* __restrict__ bm,
    float* __restrict__ oedge, float* __restrict__ omask) {
  __shared__ unsigned lbm[BM_W0];  // 64 KiB
  int t = threadIdx.x;
  long long e = (long long)blockIdx.x * EB_EDGES + (long long)t * 8;
  bool act = (e + 8 <= (long long)N_EDGES);  // N_EDGES % 8 == 0 -> all-or-none

  v4i a0{}, a1{}, b0{}, b1{};
  if (act) {
    a0 = __builtin_nontemporal_load((const v4i*)(ei + e));
    a1 = __builtin_nontemporal_load((const v4i*)(ei + e) + 1);
    b0 = __builtin_nontemporal_load((const v4i*)(ei + (long long)N_EDGES + e));
    b1 = __builtin_nontemporal_load((const v4i*)(ei + (long long)N_EDGES + e) + 1);
  }
  int A[8], B[8];
#pragma unroll
  for (int j = 0; j < 4; ++j) {
    A[j] = a0[j]; A[4 + j] = a1[j];
    B[j] = b0[j]; B[4 + j] = b1[j];
  }

  // phase 1: bitmap words [0, BM_W0) -> nodes [0, NODE_SPLIT)
#pragma unroll
  for (int j = 0; j < BM_W0 / (EB_THREADS * 4); ++j)
    ((v4u*)lbm)[t + j * EB_THREADS] = ((const v4u*)bm)[t + j * EB_THREADS];
  __syncthreads();
  unsigned bA = 0, bB = 0;
  if (act) {
#pragma unroll
    for (int j = 0; j < 8; ++j) {
      if (A[j] < NODE_SPLIT) bA |= ((lbm[A[j] >> 5] >> (A[j] & 31)) & 1u) << j;
      if (B[j] < NODE_SPLIT) bB |= ((lbm[B[j] >> 5] >> (B[j] & 31)) & 1u) << j;
    }
  }
  __syncthreads();
  // phase 2: bitmap words [BM_W0, BM_WORDS) -> nodes [NODE_SPLIT, N_NODES)
  {
    const v4u* src = (const v4u*)(bm + BM_W0);
    for (int j = t; j < (BM_W1 + 3) / 4; j += EB_THREADS)
      ((v4u*)lbm)[j] = src[j];
  }
  __syncthreads();
  if (act) {
#pragma unroll
    for (int j = 0; j < 8; ++j) {
      if (A[j] >= NODE_SPLIT) {
        int q = A[j] - NODE_SPLIT;
        bA |= ((lbm[q >> 5] >> (q & 31)) & 1u) << j;
      }
      if (B[j] >= NODE_SPLIT) {
        int q = B[j] - NODE_SPLIT;
        bB |= ((lbm[q >> 5] >> (q & 31)) & 1u) << j;
      }
    }
    unsigned mm = bA & bB;
    float fa[8], fb[8], fm[8];
#pragma unroll
    for (int j = 0; j < 8; ++j) {
      bool m = (mm >> j) & 1u;
      int na = -1, nb = -1;
      if (m) { na = ni[A[j]]; nb = ni[B[j]]; }
      fa[j] = m ? (float)na : -1.0f;
      fb[j] = m ? (float)nb : -1.0f;
      fm[j] = m ? 1.0f : 0.0f;
    }
    __builtin_nontemporal_store(*(const v4f*)&fa[0], (v4f*)(oedge + e));
    __builtin_nontemporal_store(*(const v4f*)&fa[4], (v4f*)(oedge + e) + 1);
    __builtin_nontemporal_store(*(const v4f*)&fb[0], (v4f*)(oedge + (long long)N_EDGES + e));
    __builtin_nontemporal_store(*(const v4f*)&fb[4], (v4f*)(oedge + (long long)N_EDGES + e) + 1);
    __builtin_nontemporal_store(*(const v4f*)&fm[0], (v4f*)(omask + e));
    __builtin_nontemporal_store(*(const v4f*)&fm[4], (v4f*)(omask + e) + 1);
  }
}

extern "C" void kernel_launch(void* const* d_in, const int* in_sizes, int n_in,
                              void* d_out, int out_size, void* d_ws, size_t ws_size,
                              hipStream_t stream) {
  const float* x  = (const float*)d_in[0];
  const int*   ei = (const int*)d_in[1];
  const float* w  = (const float*)d_in[2];
  float* out = (float*)d_out;

  char* ws = (char*)d_ws;
  size_t off = 0;
  auto alloc = [&](size_t bytes) -> void* {
    void* ptr = ws + off;
    off += (bytes + 255) & ~size_t(255);
    return ptr;
  };
  float*    score  = (float*)alloc((size_t)N_NODES * 4);
  u64*      kp0    = (u64*)alloc((size_t)N_NODES * 8);
  u64*      kp1    = (u64*)alloc((size_t)N_NODES * 8);
  unsigned* histDM = (unsigned*)alloc((size_t)NDIG * NB * 4);
  unsigned* rowsum = (unsigned*)alloc((size_t)NDIG * 4);
  int*      ni     = (int*)alloc((size_t)N_NODES * 4);
  unsigned* bm     = (unsigned*)alloc((size_t)BM_ALLOC * 4);
  (void)ws_size; (void)in_sizes; (void)n_in; (void)out_size;

  score_kernel<<<(N_NODES + 255) / 256, 256, 0, stream>>>(x, w, score, kp0, N_NODES);

  u64* kb[2] = {kp0, kp1};
  int cur = 0;
  for (int pass = 0; pass < 4; ++pass) {
    int shift = pass * 8;
    radix_hist   <<<NB,   256, 0, stream>>>(kb[cur], N_NODES, histDM, shift);
    scan_rows    <<<NDIG, 512, 0, stream>>>(histDM, rowsum);
    radix_scatter<<<NB, STHREADS, 0, stream>>>(kb[cur], N_NODES, histDM, rowsum,
                                               kb[cur ^ 1], shift);
    cur ^= 1;
  }
  init_kernel  <<<(N_NODES + 255) / 256, 256, 0, stream>>>(ni, bm, N_NODES);
  select_kernel<<<(K_SEL + 255) / 256, 256, 0, stream>>>(kb[cur], score, x, ni, bm, out, K_SEL);
  edge_kernel  <<<(N_EDGES + EB_EDGES - 1) / EB_EDGES, EB_THREADS, 0, stream>>>(
      ei, ni, bm, out + 1500000, out + 33500000);
}